// Round 1
// 916.888 us; speedup vs baseline: 1.1744x; 1.1744x over previous
//
#include <hip/hip_runtime.h>
#include <hip/hip_bf16.h>

typedef __hip_bfloat16 bf16;

#define B_   16
#define DM   1024
#define DM2  512
#define L_   4096
#define S_   64
#define H_   64
#define W_   64

__device__ __forceinline__ float b2f(bf16 v) { return __bfloat162float(v); }

// dtype-agnostic element access: f32 ? float[] : bf16[]  (index in ELEMENTS)
__device__ __forceinline__ float ldv(const void* p, size_t i, bool f32) {
    return f32 ? ((const float*)p)[i] : b2f(((const bf16*)p)[i]);
}
__device__ __forceinline__ void stv(void* p, size_t i, float v, bool f32) {
    if (f32) ((float*)p)[i] = v;
    else     ((bf16*)p)[i] = __float2bfloat16(v);
}

// ---------------------------------------------------------------------------
// K0: detect input dtype. If x is really fp32, bf16-interpreting its low
// halves (even elements) yields ~72% NaN/huge/denormal values; if x is bf16
// they are all ~N(0,1). flag=1 -> fp32, flag=0 -> bf16.
// ---------------------------------------------------------------------------
__global__ __launch_bounds__(256) void k_detect(const void* __restrict__ x,
                                                int* __restrict__ flag) {
    const int t = threadIdx.x;
    float v = b2f(((const bf16*)x)[2 * t]);
    bool susp = !(fabsf(v) <= 100.f) || (v != 0.f && fabsf(v) < 1e-20f);
    unsigned long long m = __ballot(susp);
    __shared__ int cnt[4];
    if ((t & 63) == 0) cnt[t >> 6] = __popcll(m);
    __syncthreads();
    if (t == 0) *flag = (cnt[0] + cnt[1] + cnt[2] + cnt[3] > 32) ? 1 : 0;
}

// ---------------------------------------------------------------------------
// K1: BCdt_raw[b,s,l] = sum_d w_bcdt[s,d] * x[b,d,l] + b_bcdt[s]   (d < 512)
// Restructured for occupancy: 64-l tile per block -> grid (64,16) = 1024
// blocks = 4 blocks/CU (was 512 = 2/CU). w staged TRANSPOSED in LDS so the
// inner loop is two b128 reads (both broadcast-structured, conflict-free)
// + 16 FMA per k-step.
// ---------------------------------------------------------------------------
__global__ __launch_bounds__(256, 4) void k_bcdt(const void* __restrict__ x,
                                                 const void* __restrict__ w_bcdt,
                                                 const void* __restrict__ b_bcdt,
                                                 const int* __restrict__ flag,
                                                 float* __restrict__ raw) {
    const bool f32 = (*flag != 0);
    __shared__ alignas(16) float lx[32][68];   // [d-sub][l(64)+pad]
    __shared__ alignas(16) float lw[32][68];   // [d-sub][s(64)+pad] (w transposed)
    const int tid = threadIdx.x;
    const int l0  = blockIdx.x * 64;
    const int b   = blockIdx.y;
    const int ts  = tid >> 4;   // 0..15 -> s quad
    const int tl  = tid & 15;   // 0..15 -> l quad
    float4 acc[4];
#pragma unroll
    for (int i = 0; i < 4; ++i) acc[i] = make_float4(0.f, 0.f, 0.f, 0.f);
    const size_t xb = (size_t)b * DM * L_;
    for (int dk = 0; dk < DM2; dk += 32) {
#pragma unroll
        for (int k = 0; k < 8; ++k) {           // 32 d x 64 l
            int i = tid + k * 256;
            int di = i >> 6, li = i & 63;
            lx[di][li] = ldv(x, xb + (size_t)(dk + di) * L_ + l0 + li, f32);
        }
#pragma unroll
        for (int k = 0; k < 8; ++k) {           // 64 s x 32 d, stored transposed
            int i = tid + k * 256;
            int si = i >> 5, di = i & 31;
            lw[di][si] = ldv(w_bcdt, si * DM2 + dk + di, f32);
        }
        __syncthreads();
#pragma unroll
        for (int d = 0; d < 32; ++d) {
            float4 xv = ((const float4*)lx[d])[tl];
            float4 wv = *(const float4*)&lw[d][ts * 4];
            acc[0].x += wv.x * xv.x; acc[0].y += wv.x * xv.y;
            acc[0].z += wv.x * xv.z; acc[0].w += wv.x * xv.w;
            acc[1].x += wv.y * xv.x; acc[1].y += wv.y * xv.y;
            acc[1].z += wv.y * xv.z; acc[1].w += wv.y * xv.w;
            acc[2].x += wv.z * xv.x; acc[2].y += wv.z * xv.y;
            acc[2].z += wv.z * xv.z; acc[2].w += wv.z * xv.w;
            acc[3].x += wv.w * xv.x; acc[3].y += wv.w * xv.y;
            acc[3].z += wv.w * xv.z; acc[3].w += wv.w * xv.w;
        }
        __syncthreads();
    }
#pragma unroll
    for (int i = 0; i < 4; ++i) {
        int s = ts * 4 + i;
        float bias = ldv(b_bcdt, s, f32);
        acc[i].x += bias; acc[i].y += bias; acc[i].z += bias; acc[i].w += bias;
        ((float4*)(raw + (size_t)(b * S_ + s) * L_ + l0))[tl] = acc[i];
    }
}

// ---------------------------------------------------------------------------
// K2: depthwise 3x3 (zero pad 1) on (B,64,64,64) fp32 + b_dw
// ---------------------------------------------------------------------------
__global__ __launch_bounds__(256) void k_dw_s(const float* __restrict__ raw,
                                              const void* __restrict__ w_dw,
                                              const void* __restrict__ b_dw,
                                              const int* __restrict__ flag,
                                              float* __restrict__ conv) {
    const bool f32 = (*flag != 0);
    const int idx = blockIdx.x * 256 + threadIdx.x;
    const int p  = idx & (L_ - 1);
    const int bs = idx >> 12;
    const int s  = bs & (S_ - 1);
    const int i  = p >> 6, j = p & 63;
    const float* src = raw + (size_t)bs * L_;
    float acc = ldv(b_dw, s, f32);
#pragma unroll
    for (int di = 0; di < 3; ++di) {
        int ii = i + di - 1;
        if (ii < 0 || ii >= H_) continue;
#pragma unroll
        for (int dj = 0; dj < 3; ++dj) {
            int jj = j + dj - 1;
            if (jj < 0 || jj >= W_) continue;
            acc += ldv(w_dw, s * 9 + di * 3 + dj, f32) * src[ii * W_ + jj];
        }
    }
    conv[idx] = acc;
}

// ---------------------------------------------------------------------------
// K3: per-row softmax over L of (c2*conv + A[s]), then AB = softmax * c0*conv
// ---------------------------------------------------------------------------
__global__ __launch_bounds__(256) void k_softmax_ab(const float* __restrict__ conv,
                                                    const void* __restrict__ A,
                                                    const void* __restrict__ coeffs,
                                                    const int* __restrict__ flag,
                                                    float* __restrict__ ab) {
    const bool f32 = (*flag != 0);
    const int row = blockIdx.x;
    const int s   = row & (S_ - 1);
    const int tid = threadIdx.x;
    const float c0 = ldv(coeffs, 0, f32);
    const float c2 = ldv(coeffs, 2, f32);
    const float a  = ldv(A, s, f32);
    const float* src = conv + (size_t)row * L_;
    float v[16];
#pragma unroll
    for (int k = 0; k < 4; ++k) {
        float4 t = ((const float4*)src)[tid * 4 + k];
        v[k * 4 + 0] = t.x; v[k * 4 + 1] = t.y; v[k * 4 + 2] = t.z; v[k * 4 + 3] = t.w;
    }
    float m = -1e30f;
#pragma unroll
    for (int k = 0; k < 16; ++k) m = fmaxf(m, c2 * v[k] + a);
#pragma unroll
    for (int off = 32; off > 0; off >>= 1) m = fmaxf(m, __shfl_down(m, off));
    __shared__ float redm[4], redsum[4];
    const int wv = tid >> 6, lane = tid & 63;
    if (lane == 0) redm[wv] = m;
    __syncthreads();
    m = fmaxf(fmaxf(redm[0], redm[1]), fmaxf(redm[2], redm[3]));
    float e[16];
    float ssum = 0.f;
#pragma unroll
    for (int k = 0; k < 16; ++k) { e[k] = __expf(c2 * v[k] + a - m); ssum += e[k]; }
#pragma unroll
    for (int off = 32; off > 0; off >>= 1) ssum += __shfl_down(ssum, off);
    if (lane == 0) redsum[wv] = ssum;
    __syncthreads();
    ssum = redsum[0] + redsum[1] + redsum[2] + redsum[3];
    const float inv = 1.0f / ssum;
    float* dst = ab + (size_t)row * L_;
#pragma unroll
    for (int k = 0; k < 4; ++k) {
        float4 t;
        t.x = e[k * 4 + 0] * inv * (c0 * v[k * 4 + 0]);
        t.y = e[k * 4 + 1] * inv * (c0 * v[k * 4 + 1]);
        t.z = e[k * 4 + 2] * inv * (c0 * v[k * 4 + 2]);
        t.w = e[k * 4 + 3] * inv * (c0 * v[k * 4 + 3]);
        ((float4*)dst)[tid * 4 + k] = t;
    }
}

// ---------------------------------------------------------------------------
// K4: partial h: part[lc][b][d][s] = sum_{l in chunk} x[b,d,l] * AB[b,s,l]
// Restructured for occupancy: 32-d tile per block -> grid (16,4,16) = 1024
// blocks = 4 blocks/CU = 4 waves/SIMD (was 256 blocks = 1/CU = 1 wave/SIMD,
// VALUBusy 15.7%: pure latency stall). AB re-read 16x is L3-resident.
// ---------------------------------------------------------------------------
__global__ __launch_bounds__(256, 4) void k_hpart(const void* __restrict__ x,
                                                  const float* __restrict__ ab,
                                                  const int* __restrict__ flag,
                                                  float* __restrict__ part) {
    const bool f32 = (*flag != 0);
    __shared__ alignas(16) float xt[32][36];   // [l][d(32)+pad]
    __shared__ alignas(16) float at[32][68];   // [l][s(64)+pad]
    const int tid = threadIdx.x;
    const int d0  = blockIdx.x * 32;
    const int lc  = blockIdx.y;
    const int b   = blockIdx.z;
    const int tdi = tid >> 4;   // 0..15 -> d pair
    const int tsi = tid & 15;   // 0..15 -> s quad
    float acc[2][4];
#pragma unroll
    for (int i = 0; i < 2; ++i)
#pragma unroll
        for (int j = 0; j < 4; ++j) acc[i][j] = 0.f;
    const size_t xb = (size_t)b * DM * L_ + (size_t)d0 * L_ + lc * 1024;
    const float* abb = ab + (size_t)b * S_ * L_ + lc * 1024;
    for (int l0 = 0; l0 < 1024; l0 += 32) {
#pragma unroll
        for (int k = 0; k < 4; ++k) {           // 32 d x 32 l
            int i = tid + k * 256;
            int di = i >> 5, li = i & 31;
            xt[li][di] = ldv(x, xb + (size_t)di * L_ + l0 + li, f32);
        }
#pragma unroll
        for (int k = 0; k < 8; ++k) {           // 64 s x 32 l
            int i = tid + k * 256;
            int si = i >> 5, li = i & 31;
            at[li][si] = abb[(size_t)si * L_ + l0 + li];
        }
        __syncthreads();
#pragma unroll
        for (int l = 0; l < 32; ++l) {
            float2 xv = *(const float2*)&xt[l][tdi * 2];
            float4 av = *(const float4*)&at[l][tsi * 4];
            acc[0][0] += xv.x * av.x; acc[0][1] += xv.x * av.y;
            acc[0][2] += xv.x * av.z; acc[0][3] += xv.x * av.w;
            acc[1][0] += xv.y * av.x; acc[1][1] += xv.y * av.y;
            acc[1][2] += xv.y * av.z; acc[1][3] += xv.y * av.w;
        }
        __syncthreads();
    }
    float* pp = part + ((size_t)lc * B_ + b) * DM2 * S_;
#pragma unroll
    for (int i = 0; i < 2; ++i) {
        int d = d0 + tdi * 2 + i;
        ((float4*)(pp + (size_t)d * S_))[tsi] =
            make_float4(acc[i][0], acc[i][1], acc[i][2], acc[i][3]);
    }
}

// ---------------------------------------------------------------------------
// K5: reduce the 4 partials -> h (fp32 ws for K6 feed, out-dtype to d_out)
// ---------------------------------------------------------------------------
__global__ __launch_bounds__(256) void k_hred(const float* __restrict__ part,
                                              const int* __restrict__ flag,
                                              float* __restrict__ hf,
                                              void* __restrict__ out) {
    const bool f32 = (*flag != 0);
    const int idx = blockIdx.x * 256 + threadIdx.x;    // 16*512*64
    const size_t stride = (size_t)B_ * DM2 * S_;
    float v = part[idx] + part[idx + stride] + part[idx + 2 * stride] + part[idx + 3 * stride];
    hf[idx] = v;
    stv(out, (size_t)B_ * DM * L_ + idx, v, f32);
}

// ---------------------------------------------------------------------------
// K6 (fused): for c<512, y = dwconv3x3(c1 * h[b,c,:] @ conv[b,:,:]) + b_DW.
// ---------------------------------------------------------------------------
__global__ __launch_bounds__(256) void k_y_ssm(const float* __restrict__ hf,
                                               const float* __restrict__ conv,
                                               const void* __restrict__ coeffs,
                                               const void* __restrict__ wDW,
                                               const void* __restrict__ bDW,
                                               const int* __restrict__ flag,
                                               void* __restrict__ y) {
    const bool f32 = (*flag != 0);
    __shared__ alignas(16) float hsm[16][64];          // 4 KB
    __shared__ alignas(16) char  smem[40 * 1024];      // 40 KB, time-aliased
    float (*convc)[640] = (float(*)[640])smem;         // [8 s][640 p]
    float (*yp)[640]    = (float(*)[640])smem;         // [16 c][640 p]

    const int tid  = threadIdx.x;
    const int lane = tid & 63;
    const int w    = tid >> 6;
    const int c0   = blockIdx.x * 16;
    const int r0   = blockIdx.y * 8;
    const int b    = blockIdx.z;

#pragma unroll
    for (int k = 0; k < 4; ++k) {
        int i = tid + k * 256;
        int c = i >> 6, s = i & 63;
        hsm[c][s] = hf[((size_t)b * DM2 + c0 + c) * S_ + s];
    }

    float acc[4][10];
#pragma unroll
    for (int c = 0; c < 4; ++c)
#pragma unroll
        for (int k = 0; k < 10; ++k) acc[c][k] = 0.f;

    const float* convb = conv + (size_t)b * S_ * L_;
    const int ls  = tid >> 5;
    const int lp  = tid & 31;

    for (int s0 = 0; s0 < S_; s0 += 8) {
        __syncthreads();
#pragma unroll
        for (int k = 0; k < 20; ++k) {
            int p  = lp + 32 * k;
            int gr = r0 - 1 + (p >> 6);
            gr = gr < 0 ? 0 : (gr > 63 ? 63 : gr);
            convc[ls][p] = convb[(size_t)(s0 + ls) * L_ + gr * 64 + (p & 63)];
        }
        __syncthreads();
#pragma unroll
        for (int s = 0; s < 8; ++s) {
            float hv0 = hsm[w * 4 + 0][s0 + s];
            float hv1 = hsm[w * 4 + 1][s0 + s];
            float hv2 = hsm[w * 4 + 2][s0 + s];
            float hv3 = hsm[w * 4 + 3][s0 + s];
#pragma unroll
            for (int k = 0; k < 10; ++k) {
                float cv = convc[s][lane + 64 * k];
                acc[0][k] += hv0 * cv;
                acc[1][k] += hv1 * cv;
                acc[2][k] += hv2 * cv;
                acc[3][k] += hv3 * cv;
            }
        }
    }
    __syncthreads();

    const float c1 = ldv(coeffs, 1, f32);
#pragma unroll
    for (int c = 0; c < 4; ++c)
#pragma unroll
        for (int k = 0; k < 10; ++k) {
            int gr = r0 - 1 + k;
            float v = (gr >= 0 && gr < H_) ? acc[c][k] * c1 : 0.f;
            yp[w * 4 + c][k * 64 + lane] = v;
        }
    __syncthreads();

#pragma unroll
    for (int c4 = 0; c4 < 4; ++c4) {
        const int cl = w * 4 + c4;
        const int c  = c0 + cl;
        float ww[3][3];
#pragma unroll
        for (int di = 0; di < 3; ++di)
#pragma unroll
            for (int dj = 0; dj < 3; ++dj) ww[di][dj] = ldv(wDW, c * 9 + di * 3 + dj, f32);
        const float bias = ldv(bDW, c, f32);
#pragma unroll
        for (int row = 0; row < 8; ++row) {
            float sum = bias;
#pragma unroll
            for (int di = 0; di < 3; ++di) {
                const float* rp = &yp[cl][(row + di) * 64];
                float lft = (lane > 0)  ? rp[lane - 1] : 0.f;
                float mid = rp[lane];
                float rgt = (lane < 63) ? rp[lane + 1] : 0.f;
                sum += ww[di][0] * lft + ww[di][1] * mid + ww[di][2] * rgt;
            }
            stv(y, ((size_t)b * DM + c) * L_ + (r0 + row) * 64 + lane, sum, f32);
        }
    }
}

// ---------------------------------------------------------------------------
// K7: gate half (c>=512): depthwise 3x3 directly from x. 4 px/thread.
// ---------------------------------------------------------------------------
__global__ __launch_bounds__(256) void k_final_gate(const void* __restrict__ x,
                                                    const void* __restrict__ wDW,
                                                    const void* __restrict__ bDW,
                                                    const int* __restrict__ flag,
                                                    void* __restrict__ y) {
    const bool f32 = (*flag != 0);
    const int idx4 = blockIdx.x * 256 + threadIdx.x;
    const int j4 = (idx4 & 15) * 4;
    const int i  = (idx4 >> 4) & 63;
    const int c  = DM2 + ((idx4 >> 10) & (DM2 - 1));
    const int b  = idx4 >> 19;
    const size_t src = ((size_t)b * DM + c) * L_;
    float ww[3][3];
#pragma unroll
    for (int di = 0; di < 3; ++di)
#pragma unroll
        for (int dj = 0; dj < 3; ++dj) ww[di][dj] = ldv(wDW, c * 9 + di * 3 + dj, f32);
    const float bias = ldv(bDW, c, f32);
    float r[3][6];
#pragma unroll
    for (int di = 0; di < 3; ++di) {
        int ii = i + di - 1;
        bool rok = (ii >= 0 && ii < H_);
#pragma unroll
        for (int t = 0; t < 6; ++t) {
            int jj = j4 - 1 + t;
            r[di][t] = (rok && jj >= 0 && jj < W_) ? ldv(x, src + ii * W_ + jj, f32) : 0.f;
        }
    }
#pragma unroll
    for (int q = 0; q < 4; ++q) {
        float acc = bias;
#pragma unroll
        for (int di = 0; di < 3; ++di)
#pragma unroll
            for (int dj = 0; dj < 3; ++dj) acc += ww[di][dj] * r[di][q + dj];
        stv(y, src + i * W_ + j4 + q, acc, f32);
    }
}

// ---------------------------------------------------------------------------
// Workspace layout (42 MiB + 4 B):
//   [ 0,16M) BCdt_raw, then AB    [16M,24M) h partials
//   [24M,40M) BCdt_conv           [40M,42M) h fp32
//   [42M] dtype flag (int)
// ---------------------------------------------------------------------------
extern "C" void kernel_launch(void* const* d_in, const int* in_sizes, int n_in,
                              void* d_out, int out_size, void* d_ws, size_t ws_size,
                              hipStream_t stream) {
    const void* x      = d_in[0];
    const void* w_bcdt = d_in[1];
    const void* b_bcdt = d_in[2];
    const void* w_dw   = d_in[3];
    const void* b_dw   = d_in[4];
    const void* A      = d_in[5];
    const void* coeffs = d_in[6];
    const void* w_DW   = d_in[7];
    const void* b_DW   = d_in[8];

    char* ws = (char*)d_ws;
    float* f_raw  = (float*)ws;                          // 16 MiB (also AB)
    float* f_part = (float*)(ws + (size_t)(16 << 20));   // 8 MiB
    float* f_conv = (float*)(ws + (size_t)(24 << 20));   // 16 MiB
    float* f_hf   = (float*)(ws + (size_t)(40 << 20));   // 2 MiB
    int*   flag   = (int*)  (ws + (size_t)(42 << 20));   // 4 B

    k_detect    <<<1,               256, 0, stream>>>(x, flag);
    k_bcdt      <<<dim3(64, 16),    256, 0, stream>>>(x, w_bcdt, b_bcdt, flag, f_raw);
    k_dw_s      <<<16384,           256, 0, stream>>>(f_raw, w_dw, b_dw, flag, f_conv);
    k_softmax_ab<<<1024,            256, 0, stream>>>(f_conv, A, coeffs, flag, f_raw);
    k_hpart     <<<dim3(16, 4, 16), 256, 0, stream>>>(x, f_raw, flag, f_part);
    k_hred      <<<2048,            256, 0, stream>>>(f_part, flag, f_hf, d_out);
    k_y_ssm     <<<dim3(32, 8, 16), 256, 0, stream>>>(f_hf, f_conv, coeffs, w_DW, b_DW, flag, d_out);
    k_final_gate<<<32768,           256, 0, stream>>>(x, w_DW, b_DW, flag, d_out);
}

// Round 2
// 878.391 us; speedup vs baseline: 1.2258x; 1.0438x over previous
//
#include <hip/hip_runtime.h>
#include <hip/hip_bf16.h>

typedef __hip_bfloat16 bf16;

#define B_   16
#define DM   1024
#define DM2  512
#define L_   4096
#define S_   64
#define H_   64
#define W_   64

__device__ __forceinline__ float b2f(bf16 v) { return __bfloat162float(v); }

// dtype-agnostic element access: f32 ? float[] : bf16[]  (index in ELEMENTS)
__device__ __forceinline__ float ldv(const void* p, size_t i, bool f32) {
    return f32 ? ((const float*)p)[i] : b2f(((const bf16*)p)[i]);
}
__device__ __forceinline__ void stv(void* p, size_t i, float v, bool f32) {
    if (f32) ((float*)p)[i] = v;
    else     ((bf16*)p)[i] = __float2bfloat16(v);
}

// ---------------------------------------------------------------------------
// K0: detect input dtype. If x is really fp32, bf16-interpreting its low
// halves (even elements) yields ~72% NaN/huge/denormal values; if x is bf16
// they are all ~N(0,1). flag=1 -> fp32, flag=0 -> bf16.
// ---------------------------------------------------------------------------
__global__ __launch_bounds__(256) void k_detect(const void* __restrict__ x,
                                                int* __restrict__ flag) {
    const int t = threadIdx.x;
    float v = b2f(((const bf16*)x)[2 * t]);
    bool susp = !(fabsf(v) <= 100.f) || (v != 0.f && fabsf(v) < 1e-20f);
    unsigned long long m = __ballot(susp);
    __shared__ int cnt[4];
    if ((t & 63) == 0) cnt[t >> 6] = __popcll(m);
    __syncthreads();
    if (t == 0) *flag = (cnt[0] + cnt[1] + cnt[2] + cnt[3] > 32) ? 1 : 0;
}

// ---------------------------------------------------------------------------
// K1: BCdt_raw[b,s,l] = sum_d w_bcdt[s,d] * x[b,d,l] + b_bcdt[s]   (d < 512)
// 64-l tile per block -> grid (64,16) = 1024 blocks = 4 blocks/CU. w staged
// TRANSPOSED in LDS so the inner loop is two b128 reads + 16 FMA per k-step.
// ---------------------------------------------------------------------------
__global__ __launch_bounds__(256, 4) void k_bcdt(const void* __restrict__ x,
                                                 const void* __restrict__ w_bcdt,
                                                 const void* __restrict__ b_bcdt,
                                                 const int* __restrict__ flag,
                                                 float* __restrict__ raw) {
    const bool f32 = (*flag != 0);
    __shared__ alignas(16) float lx[32][68];   // [d-sub][l(64)+pad]
    __shared__ alignas(16) float lw[32][68];   // [d-sub][s(64)+pad] (w transposed)
    const int tid = threadIdx.x;
    const int l0  = blockIdx.x * 64;
    const int b   = blockIdx.y;
    const int ts  = tid >> 4;   // 0..15 -> s quad
    const int tl  = tid & 15;   // 0..15 -> l quad
    float4 acc[4];
#pragma unroll
    for (int i = 0; i < 4; ++i) acc[i] = make_float4(0.f, 0.f, 0.f, 0.f);
    const size_t xb = (size_t)b * DM * L_;
    for (int dk = 0; dk < DM2; dk += 32) {
#pragma unroll
        for (int k = 0; k < 8; ++k) {           // 32 d x 64 l
            int i = tid + k * 256;
            int di = i >> 6, li = i & 63;
            lx[di][li] = ldv(x, xb + (size_t)(dk + di) * L_ + l0 + li, f32);
        }
#pragma unroll
        for (int k = 0; k < 8; ++k) {           // 64 s x 32 d, stored transposed
            int i = tid + k * 256;
            int si = i >> 5, di = i & 31;
            lw[di][si] = ldv(w_bcdt, si * DM2 + dk + di, f32);
        }
        __syncthreads();
#pragma unroll
        for (int d = 0; d < 32; ++d) {
            float4 xv = ((const float4*)lx[d])[tl];
            float4 wv = *(const float4*)&lw[d][ts * 4];
            acc[0].x += wv.x * xv.x; acc[0].y += wv.x * xv.y;
            acc[0].z += wv.x * xv.z; acc[0].w += wv.x * xv.w;
            acc[1].x += wv.y * xv.x; acc[1].y += wv.y * xv.y;
            acc[1].z += wv.y * xv.z; acc[1].w += wv.y * xv.w;
            acc[2].x += wv.z * xv.x; acc[2].y += wv.z * xv.y;
            acc[2].z += wv.z * xv.z; acc[2].w += wv.z * xv.w;
            acc[3].x += wv.w * xv.x; acc[3].y += wv.w * xv.y;
            acc[3].z += wv.w * xv.z; acc[3].w += wv.w * xv.w;
        }
        __syncthreads();
    }
#pragma unroll
    for (int i = 0; i < 4; ++i) {
        int s = ts * 4 + i;
        float bias = ldv(b_bcdt, s, f32);
        acc[i].x += bias; acc[i].y += bias; acc[i].z += bias; acc[i].w += bias;
        ((float4*)(raw + (size_t)(b * S_ + s) * L_ + l0))[tl] = acc[i];
    }
}

// ---------------------------------------------------------------------------
// K2: depthwise 3x3 (zero pad 1) on (B,64,64,64) fp32 + b_dw
// ---------------------------------------------------------------------------
__global__ __launch_bounds__(256) void k_dw_s(const float* __restrict__ raw,
                                              const void* __restrict__ w_dw,
                                              const void* __restrict__ b_dw,
                                              const int* __restrict__ flag,
                                              float* __restrict__ conv) {
    const bool f32 = (*flag != 0);
    const int idx = blockIdx.x * 256 + threadIdx.x;
    const int p  = idx & (L_ - 1);
    const int bs = idx >> 12;
    const int s  = bs & (S_ - 1);
    const int i  = p >> 6, j = p & 63;
    const float* src = raw + (size_t)bs * L_;
    float acc = ldv(b_dw, s, f32);
#pragma unroll
    for (int di = 0; di < 3; ++di) {
        int ii = i + di - 1;
        if (ii < 0 || ii >= H_) continue;
#pragma unroll
        for (int dj = 0; dj < 3; ++dj) {
            int jj = j + dj - 1;
            if (jj < 0 || jj >= W_) continue;
            acc += ldv(w_dw, s * 9 + di * 3 + dj, f32) * src[ii * W_ + jj];
        }
    }
    conv[idx] = acc;
}

// ---------------------------------------------------------------------------
// K3: per-row softmax over L of (c2*conv + A[s]), then AB = softmax * c0*conv
// ---------------------------------------------------------------------------
__global__ __launch_bounds__(256) void k_softmax_ab(const float* __restrict__ conv,
                                                    const void* __restrict__ A,
                                                    const void* __restrict__ coeffs,
                                                    const int* __restrict__ flag,
                                                    float* __restrict__ ab) {
    const bool f32 = (*flag != 0);
    const int row = blockIdx.x;
    const int s   = row & (S_ - 1);
    const int tid = threadIdx.x;
    const float c0 = ldv(coeffs, 0, f32);
    const float c2 = ldv(coeffs, 2, f32);
    const float a  = ldv(A, s, f32);
    const float* src = conv + (size_t)row * L_;
    float v[16];
#pragma unroll
    for (int k = 0; k < 4; ++k) {
        float4 t = ((const float4*)src)[tid * 4 + k];
        v[k * 4 + 0] = t.x; v[k * 4 + 1] = t.y; v[k * 4 + 2] = t.z; v[k * 4 + 3] = t.w;
    }
    float m = -1e30f;
#pragma unroll
    for (int k = 0; k < 16; ++k) m = fmaxf(m, c2 * v[k] + a);
#pragma unroll
    for (int off = 32; off > 0; off >>= 1) m = fmaxf(m, __shfl_down(m, off));
    __shared__ float redm[4], redsum[4];
    const int wv = tid >> 6, lane = tid & 63;
    if (lane == 0) redm[wv] = m;
    __syncthreads();
    m = fmaxf(fmaxf(redm[0], redm[1]), fmaxf(redm[2], redm[3]));
    float e[16];
    float ssum = 0.f;
#pragma unroll
    for (int k = 0; k < 16; ++k) { e[k] = __expf(c2 * v[k] + a - m); ssum += e[k]; }
#pragma unroll
    for (int off = 32; off > 0; off >>= 1) ssum += __shfl_down(ssum, off);
    if (lane == 0) redsum[wv] = ssum;
    __syncthreads();
    ssum = redsum[0] + redsum[1] + redsum[2] + redsum[3];
    const float inv = 1.0f / ssum;
    float* dst = ab + (size_t)row * L_;
#pragma unroll
    for (int k = 0; k < 4; ++k) {
        float4 t;
        t.x = e[k * 4 + 0] * inv * (c0 * v[k * 4 + 0]);
        t.y = e[k * 4 + 1] * inv * (c0 * v[k * 4 + 1]);
        t.z = e[k * 4 + 2] * inv * (c0 * v[k * 4 + 2]);
        t.w = e[k * 4 + 3] * inv * (c0 * v[k * 4 + 3]);
        ((float4*)dst)[tid * 4 + k] = t;
    }
}

// ---------------------------------------------------------------------------
// K4: partial h: part[lc][b][d][s] = sum_{l in chunk} x[b,d,l] * AB[b,s,l]
// 32-d tile per block -> grid (16,4,16) = 1024 blocks = 4 blocks/CU.
// ---------------------------------------------------------------------------
__global__ __launch_bounds__(256, 4) void k_hpart(const void* __restrict__ x,
                                                  const float* __restrict__ ab,
                                                  const int* __restrict__ flag,
                                                  float* __restrict__ part) {
    const bool f32 = (*flag != 0);
    __shared__ alignas(16) float xt[32][36];   // [l][d(32)+pad]
    __shared__ alignas(16) float at[32][68];   // [l][s(64)+pad]
    const int tid = threadIdx.x;
    const int d0  = blockIdx.x * 32;
    const int lc  = blockIdx.y;
    const int b   = blockIdx.z;
    const int tdi = tid >> 4;   // 0..15 -> d pair
    const int tsi = tid & 15;   // 0..15 -> s quad
    float acc[2][4];
#pragma unroll
    for (int i = 0; i < 2; ++i)
#pragma unroll
        for (int j = 0; j < 4; ++j) acc[i][j] = 0.f;
    const size_t xb = (size_t)b * DM * L_ + (size_t)d0 * L_ + lc * 1024;
    const float* abb = ab + (size_t)b * S_ * L_ + lc * 1024;
    for (int l0 = 0; l0 < 1024; l0 += 32) {
#pragma unroll
        for (int k = 0; k < 4; ++k) {           // 32 d x 32 l
            int i = tid + k * 256;
            int di = i >> 5, li = i & 31;
            xt[li][di] = ldv(x, xb + (size_t)di * L_ + l0 + li, f32);
        }
#pragma unroll
        for (int k = 0; k < 8; ++k) {           // 64 s x 32 l
            int i = tid + k * 256;
            int si = i >> 5, li = i & 31;
            at[li][si] = abb[(size_t)si * L_ + l0 + li];
        }
        __syncthreads();
#pragma unroll
        for (int l = 0; l < 32; ++l) {
            float2 xv = *(const float2*)&xt[l][tdi * 2];
            float4 av = *(const float4*)&at[l][tsi * 4];
            acc[0][0] += xv.x * av.x; acc[0][1] += xv.x * av.y;
            acc[0][2] += xv.x * av.z; acc[0][3] += xv.x * av.w;
            acc[1][0] += xv.y * av.x; acc[1][1] += xv.y * av.y;
            acc[1][2] += xv.y * av.z; acc[1][3] += xv.y * av.w;
        }
        __syncthreads();
    }
    float* pp = part + ((size_t)lc * B_ + b) * DM2 * S_;
#pragma unroll
    for (int i = 0; i < 2; ++i) {
        int d = d0 + tdi * 2 + i;
        ((float4*)(pp + (size_t)d * S_))[tsi] =
            make_float4(acc[i][0], acc[i][1], acc[i][2], acc[i][3]);
    }
}

// ---------------------------------------------------------------------------
// K5: reduce the 4 partials -> h (fp32 ws for K6 feed, out-dtype to d_out)
// ---------------------------------------------------------------------------
__global__ __launch_bounds__(256) void k_hred(const float* __restrict__ part,
                                              const int* __restrict__ flag,
                                              float* __restrict__ hf,
                                              void* __restrict__ out) {
    const bool f32 = (*flag != 0);
    const int idx = blockIdx.x * 256 + threadIdx.x;    // 16*512*64
    const size_t stride = (size_t)B_ * DM2 * S_;
    float v = part[idx] + part[idx + stride] + part[idx + 2 * stride] + part[idx + 3 * stride];
    hf[idx] = v;
    stv(out, (size_t)B_ * DM * L_ + idx, v, f32);
}

// ---------------------------------------------------------------------------
// K6 (fused): for c<512, y = dwconv3x3(c1 * h[b,c,:] @ conv[b,:,:]) + b_DW.
// v2: dwconv epilogue done entirely in registers + __shfl for lane+-1 column
// neighbors (row neighbors are in-thread: acc[c][k+-1]). Deletes the 40 KB
// yp LDS buffer (44 -> 24.25 KB, 3 -> ~5 blocks/CU) and ~330 LDS ops/thread.
// ---------------------------------------------------------------------------
__global__ __launch_bounds__(256) void k_y_ssm(const float* __restrict__ hf,
                                               const float* __restrict__ conv,
                                               const void* __restrict__ coeffs,
                                               const void* __restrict__ wDW,
                                               const void* __restrict__ bDW,
                                               const int* __restrict__ flag,
                                               void* __restrict__ y) {
    const bool f32 = (*flag != 0);
    __shared__ alignas(16) float hsm[16][64];          // 4 KB
    __shared__ alignas(16) float convc[8][640];        // 20 KB

    const int tid  = threadIdx.x;
    const int lane = tid & 63;
    const int w    = tid >> 6;
    const int c0   = blockIdx.x * 16;
    const int r0   = blockIdx.y * 8;
    const int b    = blockIdx.z;

#pragma unroll
    for (int k = 0; k < 4; ++k) {
        int i = tid + k * 256;
        int c = i >> 6, s = i & 63;
        hsm[c][s] = hf[((size_t)b * DM2 + c0 + c) * S_ + s];
    }

    float acc[4][10];
#pragma unroll
    for (int c = 0; c < 4; ++c)
#pragma unroll
        for (int k = 0; k < 10; ++k) acc[c][k] = 0.f;

    const float* convb = conv + (size_t)b * S_ * L_;
    const int ls  = tid >> 5;
    const int lp  = tid & 31;

    for (int s0 = 0; s0 < S_; s0 += 8) {
        __syncthreads();
#pragma unroll
        for (int k = 0; k < 20; ++k) {
            int p  = lp + 32 * k;
            int gr = r0 - 1 + (p >> 6);
            gr = gr < 0 ? 0 : (gr > 63 ? 63 : gr);
            convc[ls][p] = convb[(size_t)(s0 + ls) * L_ + gr * 64 + (p & 63)];
        }
        __syncthreads();
#pragma unroll
        for (int s = 0; s < 8; ++s) {
            float hv0 = hsm[w * 4 + 0][s0 + s];
            float hv1 = hsm[w * 4 + 1][s0 + s];
            float hv2 = hsm[w * 4 + 2][s0 + s];
            float hv3 = hsm[w * 4 + 3][s0 + s];
#pragma unroll
            for (int k = 0; k < 10; ++k) {
                float cv = convc[s][lane + 64 * k];
                acc[0][k] += hv0 * cv;
                acc[1][k] += hv1 * cv;
                acc[2][k] += hv2 * cv;
                acc[3][k] += hv3 * cv;
            }
        }
    }

    const float c1 = ldv(coeffs, 1, f32);
#pragma unroll
    for (int c4 = 0; c4 < 4; ++c4) {
        const int cl = w * 4 + c4;
        const int c  = c0 + cl;
        float ww[3][3];
#pragma unroll
        for (int di = 0; di < 3; ++di)
#pragma unroll
            for (int dj = 0; dj < 3; ++dj) ww[di][dj] = ldv(wDW, c * 9 + di * 3 + dj, f32);
        const float bias = ldv(bDW, c, f32);

        // scaled + row-boundary-masked column of 10 rows, in registers
        float vm[10], vl[10], vr[10];
#pragma unroll
        for (int k = 0; k < 10; ++k) {
            int gr = r0 - 1 + k;
            float v = (gr >= 0 && gr < H_) ? acc[c4][k] * c1 : 0.f;
            vm[k] = v;
            float lf = __shfl_up(v, 1);
            float rt = __shfl_down(v, 1);
            vl[k] = (lane > 0)  ? lf : 0.f;
            vr[k] = (lane < 63) ? rt : 0.f;
        }
#pragma unroll
        for (int row = 0; row < 8; ++row) {
            float sum = bias;
#pragma unroll
            for (int di = 0; di < 3; ++di) {
                sum += ww[di][0] * vl[row + di]
                     + ww[di][1] * vm[row + di]
                     + ww[di][2] * vr[row + di];
            }
            stv(y, ((size_t)b * DM + c) * L_ + (r0 + row) * 64 + lane, sum, f32);
        }
    }
}

// ---------------------------------------------------------------------------
// K7: gate half (c>=512): depthwise 3x3 directly from x. 4 px/thread.
// ---------------------------------------------------------------------------
__global__ __launch_bounds__(256) void k_final_gate(const void* __restrict__ x,
                                                    const void* __restrict__ wDW,
                                                    const void* __restrict__ bDW,
                                                    const int* __restrict__ flag,
                                                    void* __restrict__ y) {
    const bool f32 = (*flag != 0);
    const int idx4 = blockIdx.x * 256 + threadIdx.x;
    const int j4 = (idx4 & 15) * 4;
    const int i  = (idx4 >> 4) & 63;
    const int c  = DM2 + ((idx4 >> 10) & (DM2 - 1));
    const int b  = idx4 >> 19;
    const size_t src = ((size_t)b * DM + c) * L_;
    float ww[3][3];
#pragma unroll
    for (int di = 0; di < 3; ++di)
#pragma unroll
        for (int dj = 0; dj < 3; ++dj) ww[di][dj] = ldv(wDW, c * 9 + di * 3 + dj, f32);
    const float bias = ldv(bDW, c, f32);
    float r[3][6];
#pragma unroll
    for (int di = 0; di < 3; ++di) {
        int ii = i + di - 1;
        bool rok = (ii >= 0 && ii < H_);
#pragma unroll
        for (int t = 0; t < 6; ++t) {
            int jj = j4 - 1 + t;
            r[di][t] = (rok && jj >= 0 && jj < W_) ? ldv(x, src + ii * W_ + jj, f32) : 0.f;
        }
    }
#pragma unroll
    for (int q = 0; q < 4; ++q) {
        float acc = bias;
#pragma unroll
        for (int di = 0; di < 3; ++di)
#pragma unroll
            for (int dj = 0; dj < 3; ++dj) acc += ww[di][dj] * r[di][q + dj];
        stv(y, src + i * W_ + j4 + q, acc, f32);
    }
}

// ---------------------------------------------------------------------------
// Workspace layout (42 MiB + 4 B):
//   [ 0,16M) BCdt_raw, then AB    [16M,24M) h partials
//   [24M,40M) BCdt_conv           [40M,42M) h fp32
//   [42M] dtype flag (int)
// ---------------------------------------------------------------------------
extern "C" void kernel_launch(void* const* d_in, const int* in_sizes, int n_in,
                              void* d_out, int out_size, void* d_ws, size_t ws_size,
                              hipStream_t stream) {
    const void* x      = d_in[0];
    const void* w_bcdt = d_in[1];
    const void* b_bcdt = d_in[2];
    const void* w_dw   = d_in[3];
    const void* b_dw   = d_in[4];
    const void* A      = d_in[5];
    const void* coeffs = d_in[6];
    const void* w_DW   = d_in[7];
    const void* b_DW   = d_in[8];

    char* ws = (char*)d_ws;
    float* f_raw  = (float*)ws;                          // 16 MiB (also AB)
    float* f_part = (float*)(ws + (size_t)(16 << 20));   // 8 MiB
    float* f_conv = (float*)(ws + (size_t)(24 << 20));   // 16 MiB
    float* f_hf   = (float*)(ws + (size_t)(40 << 20));   // 2 MiB
    int*   flag   = (int*)  (ws + (size_t)(42 << 20));   // 4 B

    k_detect    <<<1,               256, 0, stream>>>(x, flag);
    k_bcdt      <<<dim3(64, 16),    256, 0, stream>>>(x, w_bcdt, b_bcdt, flag, f_raw);
    k_dw_s      <<<16384,           256, 0, stream>>>(f_raw, w_dw, b_dw, flag, f_conv);
    k_softmax_ab<<<1024,            256, 0, stream>>>(f_conv, A, coeffs, flag, f_raw);
    k_hpart     <<<dim3(16, 4, 16), 256, 0, stream>>>(x, f_raw, flag, f_part);
    k_hred      <<<2048,            256, 0, stream>>>(f_part, flag, f_hf, d_out);
    k_y_ssm     <<<dim3(32, 8, 16), 256, 0, stream>>>(f_hf, f_conv, coeffs, w_DW, b_DW, flag, d_out);
    k_final_gate<<<32768,           256, 0, stream>>>(x, w_DW, b_DW, flag, d_out);
}

// Round 3
// 821.526 us; speedup vs baseline: 1.3107x; 1.0692x over previous
//
#include <hip/hip_runtime.h>
#include <hip/hip_bf16.h>

typedef __hip_bfloat16 bf16;

#define B_   16
#define DM   1024
#define DM2  512
#define L_   4096
#define S_   64
#define H_   64
#define W_   64

__device__ __forceinline__ float b2f(bf16 v) { return __bfloat162float(v); }

// dtype-agnostic element access: f32 ? float[] : bf16[]  (index in ELEMENTS)
__device__ __forceinline__ float ldv(const void* p, size_t i, bool f32) {
    return f32 ? ((const float*)p)[i] : b2f(((const bf16*)p)[i]);
}
__device__ __forceinline__ void stv(void* p, size_t i, float v, bool f32) {
    if (f32) ((float*)p)[i] = v;
    else     ((bf16*)p)[i] = __float2bfloat16(v);
}

// ---------------------------------------------------------------------------
// K0: detect input dtype. If x is really fp32, bf16-interpreting its low
// halves (even elements) yields ~72% NaN/huge/denormal values; if x is bf16
// they are all ~N(0,1). flag=1 -> fp32, flag=0 -> bf16.
// ---------------------------------------------------------------------------
__global__ __launch_bounds__(256) void k_detect(const void* __restrict__ x,
                                                int* __restrict__ flag) {
    const int t = threadIdx.x;
    float v = b2f(((const bf16*)x)[2 * t]);
    bool susp = !(fabsf(v) <= 100.f) || (v != 0.f && fabsf(v) < 1e-20f);
    unsigned long long m = __ballot(susp);
    __shared__ int cnt[4];
    if ((t & 63) == 0) cnt[t >> 6] = __popcll(m);
    __syncthreads();
    if (t == 0) *flag = (cnt[0] + cnt[1] + cnt[2] + cnt[3] > 32) ? 1 : 0;
}

// ---------------------------------------------------------------------------
// K1: BCdt_raw[b,s,l] = sum_d w_bcdt[s,d] * x[b,d,l] + b_bcdt[s]   (d < 512)
// 64-l tile per block -> grid (64,16) = 1024 blocks = 4 blocks/CU. w staged
// TRANSPOSED in LDS so the inner loop is two b128 reads + 16 FMA per k-step.
// ---------------------------------------------------------------------------
__global__ __launch_bounds__(256, 4) void k_bcdt(const void* __restrict__ x,
                                                 const void* __restrict__ w_bcdt,
                                                 const void* __restrict__ b_bcdt,
                                                 const int* __restrict__ flag,
                                                 float* __restrict__ raw) {
    const bool f32 = (*flag != 0);
    __shared__ alignas(16) float lx[32][68];   // [d-sub][l(64)+pad]
    __shared__ alignas(16) float lw[32][68];   // [d-sub][s(64)+pad] (w transposed)
    const int tid = threadIdx.x;
    const int l0  = blockIdx.x * 64;
    const int b   = blockIdx.y;
    const int ts  = tid >> 4;   // 0..15 -> s quad
    const int tl  = tid & 15;   // 0..15 -> l quad
    float4 acc[4];
#pragma unroll
    for (int i = 0; i < 4; ++i) acc[i] = make_float4(0.f, 0.f, 0.f, 0.f);
    const size_t xb = (size_t)b * DM * L_;
    for (int dk = 0; dk < DM2; dk += 32) {
#pragma unroll
        for (int k = 0; k < 8; ++k) {           // 32 d x 64 l
            int i = tid + k * 256;
            int di = i >> 6, li = i & 63;
            lx[di][li] = ldv(x, xb + (size_t)(dk + di) * L_ + l0 + li, f32);
        }
#pragma unroll
        for (int k = 0; k < 8; ++k) {           // 64 s x 32 d, stored transposed
            int i = tid + k * 256;
            int si = i >> 5, di = i & 31;
            lw[di][si] = ldv(w_bcdt, si * DM2 + dk + di, f32);
        }
        __syncthreads();
#pragma unroll
        for (int d = 0; d < 32; ++d) {
            float4 xv = ((const float4*)lx[d])[tl];
            float4 wv = *(const float4*)&lw[d][ts * 4];
            acc[0].x += wv.x * xv.x; acc[0].y += wv.x * xv.y;
            acc[0].z += wv.x * xv.z; acc[0].w += wv.x * xv.w;
            acc[1].x += wv.y * xv.x; acc[1].y += wv.y * xv.y;
            acc[1].z += wv.y * xv.z; acc[1].w += wv.y * xv.w;
            acc[2].x += wv.z * xv.x; acc[2].y += wv.z * xv.y;
            acc[2].z += wv.z * xv.z; acc[2].w += wv.z * xv.w;
            acc[3].x += wv.w * xv.x; acc[3].y += wv.w * xv.y;
            acc[3].z += wv.w * xv.z; acc[3].w += wv.w * xv.w;
        }
        __syncthreads();
    }
#pragma unroll
    for (int i = 0; i < 4; ++i) {
        int s = ts * 4 + i;
        float bias = ldv(b_bcdt, s, f32);
        acc[i].x += bias; acc[i].y += bias; acc[i].z += bias; acc[i].w += bias;
        ((float4*)(raw + (size_t)(b * S_ + s) * L_ + l0))[tl] = acc[i];
    }
}

// ---------------------------------------------------------------------------
// K2: depthwise 3x3 (zero pad 1) on (B,64,64,64) fp32 + b_dw
// ---------------------------------------------------------------------------
__global__ __launch_bounds__(256) void k_dw_s(const float* __restrict__ raw,
                                              const void* __restrict__ w_dw,
                                              const void* __restrict__ b_dw,
                                              const int* __restrict__ flag,
                                              float* __restrict__ conv) {
    const bool f32 = (*flag != 0);
    const int idx = blockIdx.x * 256 + threadIdx.x;
    const int p  = idx & (L_ - 1);
    const int bs = idx >> 12;
    const int s  = bs & (S_ - 1);
    const int i  = p >> 6, j = p & 63;
    const float* src = raw + (size_t)bs * L_;
    float acc = ldv(b_dw, s, f32);
#pragma unroll
    for (int di = 0; di < 3; ++di) {
        int ii = i + di - 1;
        if (ii < 0 || ii >= H_) continue;
#pragma unroll
        for (int dj = 0; dj < 3; ++dj) {
            int jj = j + dj - 1;
            if (jj < 0 || jj >= W_) continue;
            acc += ldv(w_dw, s * 9 + di * 3 + dj, f32) * src[ii * W_ + jj];
        }
    }
    conv[idx] = acc;
}

// ---------------------------------------------------------------------------
// K3: per-row softmax over L of (c2*conv + A[s]), then AB = softmax * c0*conv
// ---------------------------------------------------------------------------
__global__ __launch_bounds__(256) void k_softmax_ab(const float* __restrict__ conv,
                                                    const void* __restrict__ A,
                                                    const void* __restrict__ coeffs,
                                                    const int* __restrict__ flag,
                                                    float* __restrict__ ab) {
    const bool f32 = (*flag != 0);
    const int row = blockIdx.x;
    const int s   = row & (S_ - 1);
    const int tid = threadIdx.x;
    const float c0 = ldv(coeffs, 0, f32);
    const float c2 = ldv(coeffs, 2, f32);
    const float a  = ldv(A, s, f32);
    const float* src = conv + (size_t)row * L_;
    float v[16];
#pragma unroll
    for (int k = 0; k < 4; ++k) {
        float4 t = ((const float4*)src)[tid * 4 + k];
        v[k * 4 + 0] = t.x; v[k * 4 + 1] = t.y; v[k * 4 + 2] = t.z; v[k * 4 + 3] = t.w;
    }
    float m = -1e30f;
#pragma unroll
    for (int k = 0; k < 16; ++k) m = fmaxf(m, c2 * v[k] + a);
#pragma unroll
    for (int off = 32; off > 0; off >>= 1) m = fmaxf(m, __shfl_down(m, off));
    __shared__ float redm[4], redsum[4];
    const int wv = tid >> 6, lane = tid & 63;
    if (lane == 0) redm[wv] = m;
    __syncthreads();
    m = fmaxf(fmaxf(redm[0], redm[1]), fmaxf(redm[2], redm[3]));
    float e[16];
    float ssum = 0.f;
#pragma unroll
    for (int k = 0; k < 16; ++k) { e[k] = __expf(c2 * v[k] + a - m); ssum += e[k]; }
#pragma unroll
    for (int off = 32; off > 0; off >>= 1) ssum += __shfl_down(ssum, off);
    if (lane == 0) redsum[wv] = ssum;
    __syncthreads();
    ssum = redsum[0] + redsum[1] + redsum[2] + redsum[3];
    const float inv = 1.0f / ssum;
    float* dst = ab + (size_t)row * L_;
#pragma unroll
    for (int k = 0; k < 4; ++k) {
        float4 t;
        t.x = e[k * 4 + 0] * inv * (c0 * v[k * 4 + 0]);
        t.y = e[k * 4 + 1] * inv * (c0 * v[k * 4 + 1]);
        t.z = e[k * 4 + 2] * inv * (c0 * v[k * 4 + 2]);
        t.w = e[k * 4 + 3] * inv * (c0 * v[k * 4 + 3]);
        ((float4*)dst)[tid * 4 + k] = t;
    }
}

// ---------------------------------------------------------------------------
// K4: partial h: part[lc][b][d][s] = sum_{l in chunk} x[b,d,l] * AB[b,s,l]
// 32-d tile per block -> grid (16,4,16) = 1024 blocks = 4 blocks/CU.
// ---------------------------------------------------------------------------
__global__ __launch_bounds__(256, 4) void k_hpart(const void* __restrict__ x,
                                                  const float* __restrict__ ab,
                                                  const int* __restrict__ flag,
                                                  float* __restrict__ part) {
    const bool f32 = (*flag != 0);
    __shared__ alignas(16) float xt[32][36];   // [l][d(32)+pad]
    __shared__ alignas(16) float at[32][68];   // [l][s(64)+pad]
    const int tid = threadIdx.x;
    const int d0  = blockIdx.x * 32;
    const int lc  = blockIdx.y;
    const int b   = blockIdx.z;
    const int tdi = tid >> 4;   // 0..15 -> d pair
    const int tsi = tid & 15;   // 0..15 -> s quad
    float acc[2][4];
#pragma unroll
    for (int i = 0; i < 2; ++i)
#pragma unroll
        for (int j = 0; j < 4; ++j) acc[i][j] = 0.f;
    const size_t xb = (size_t)b * DM * L_ + (size_t)d0 * L_ + lc * 1024;
    const float* abb = ab + (size_t)b * S_ * L_ + lc * 1024;
    for (int l0 = 0; l0 < 1024; l0 += 32) {
#pragma unroll
        for (int k = 0; k < 4; ++k) {           // 32 d x 32 l
            int i = tid + k * 256;
            int di = i >> 5, li = i & 31;
            xt[li][di] = ldv(x, xb + (size_t)di * L_ + l0 + li, f32);
        }
#pragma unroll
        for (int k = 0; k < 8; ++k) {           // 64 s x 32 l
            int i = tid + k * 256;
            int si = i >> 5, li = i & 31;
            at[li][si] = abb[(size_t)si * L_ + l0 + li];
        }
        __syncthreads();
#pragma unroll
        for (int l = 0; l < 32; ++l) {
            float2 xv = *(const float2*)&xt[l][tdi * 2];
            float4 av = *(const float4*)&at[l][tsi * 4];
            acc[0][0] += xv.x * av.x; acc[0][1] += xv.x * av.y;
            acc[0][2] += xv.x * av.z; acc[0][3] += xv.x * av.w;
            acc[1][0] += xv.y * av.x; acc[1][1] += xv.y * av.y;
            acc[1][2] += xv.y * av.z; acc[1][3] += xv.y * av.w;
        }
        __syncthreads();
    }
    float* pp = part + ((size_t)lc * B_ + b) * DM2 * S_;
#pragma unroll
    for (int i = 0; i < 2; ++i) {
        int d = d0 + tdi * 2 + i;
        ((float4*)(pp + (size_t)d * S_))[tsi] =
            make_float4(acc[i][0], acc[i][1], acc[i][2], acc[i][3]);
    }
}

// ---------------------------------------------------------------------------
// K5: reduce the 4 partials -> h (fp32 ws for K6 feed, out-dtype to d_out)
// ---------------------------------------------------------------------------
__global__ __launch_bounds__(256) void k_hred(const float* __restrict__ part,
                                              const int* __restrict__ flag,
                                              float* __restrict__ hf,
                                              void* __restrict__ out) {
    const bool f32 = (*flag != 0);
    const int idx = blockIdx.x * 256 + threadIdx.x;    // 16*512*64
    const size_t stride = (size_t)B_ * DM2 * S_;
    float v = part[idx] + part[idx + stride] + part[idx + 2 * stride] + part[idx + 3 * stride];
    hf[idx] = v;
    stv(out, (size_t)B_ * DM * L_ + idx, v, f32);
}

// ---------------------------------------------------------------------------
// K6 (fused): for c<512, y = dwconv3x3(c1 * h[b,c,:] @ conv[b,:,:]) + b_DW.
// dwconv epilogue in registers + __shfl for lane+-1 column neighbors.
// ---------------------------------------------------------------------------
__global__ __launch_bounds__(256) void k_y_ssm(const float* __restrict__ hf,
                                               const float* __restrict__ conv,
                                               const void* __restrict__ coeffs,
                                               const void* __restrict__ wDW,
                                               const void* __restrict__ bDW,
                                               const int* __restrict__ flag,
                                               void* __restrict__ y) {
    const bool f32 = (*flag != 0);
    __shared__ alignas(16) float hsm[16][64];          // 4 KB
    __shared__ alignas(16) float convc[8][640];        // 20 KB

    const int tid  = threadIdx.x;
    const int lane = tid & 63;
    const int w    = tid >> 6;
    const int c0   = blockIdx.x * 16;
    const int r0   = blockIdx.y * 8;
    const int b    = blockIdx.z;

#pragma unroll
    for (int k = 0; k < 4; ++k) {
        int i = tid + k * 256;
        int c = i >> 6, s = i & 63;
        hsm[c][s] = hf[((size_t)b * DM2 + c0 + c) * S_ + s];
    }

    float acc[4][10];
#pragma unroll
    for (int c = 0; c < 4; ++c)
#pragma unroll
        for (int k = 0; k < 10; ++k) acc[c][k] = 0.f;

    const float* convb = conv + (size_t)b * S_ * L_;
    const int ls  = tid >> 5;
    const int lp  = tid & 31;

    for (int s0 = 0; s0 < S_; s0 += 8) {
        __syncthreads();
#pragma unroll
        for (int k = 0; k < 20; ++k) {
            int p  = lp + 32 * k;
            int gr = r0 - 1 + (p >> 6);
            gr = gr < 0 ? 0 : (gr > 63 ? 63 : gr);
            convc[ls][p] = convb[(size_t)(s0 + ls) * L_ + gr * 64 + (p & 63)];
        }
        __syncthreads();
#pragma unroll
        for (int s = 0; s < 8; ++s) {
            float hv0 = hsm[w * 4 + 0][s0 + s];
            float hv1 = hsm[w * 4 + 1][s0 + s];
            float hv2 = hsm[w * 4 + 2][s0 + s];
            float hv3 = hsm[w * 4 + 3][s0 + s];
#pragma unroll
            for (int k = 0; k < 10; ++k) {
                float cv = convc[s][lane + 64 * k];
                acc[0][k] += hv0 * cv;
                acc[1][k] += hv1 * cv;
                acc[2][k] += hv2 * cv;
                acc[3][k] += hv3 * cv;
            }
        }
    }

    const float c1 = ldv(coeffs, 1, f32);
#pragma unroll
    for (int c4 = 0; c4 < 4; ++c4) {
        const int cl = w * 4 + c4;
        const int c  = c0 + cl;
        float ww[3][3];
#pragma unroll
        for (int di = 0; di < 3; ++di)
#pragma unroll
            for (int dj = 0; dj < 3; ++dj) ww[di][dj] = ldv(wDW, c * 9 + di * 3 + dj, f32);
        const float bias = ldv(bDW, c, f32);

        // scaled + row-boundary-masked column of 10 rows, in registers
        float vm[10], vl[10], vr[10];
#pragma unroll
        for (int k = 0; k < 10; ++k) {
            int gr = r0 - 1 + k;
            float v = (gr >= 0 && gr < H_) ? acc[c4][k] * c1 : 0.f;
            vm[k] = v;
            float lf = __shfl_up(v, 1);
            float rt = __shfl_down(v, 1);
            vl[k] = (lane > 0)  ? lf : 0.f;
            vr[k] = (lane < 63) ? rt : 0.f;
        }
#pragma unroll
        for (int row = 0; row < 8; ++row) {
            float sum = bias;
#pragma unroll
            for (int di = 0; di < 3; ++di) {
                sum += ww[di][0] * vl[row + di]
                     + ww[di][1] * vm[row + di]
                     + ww[di][2] * vr[row + di];
            }
            stv(y, ((size_t)b * DM + c) * L_ + (r0 + row) * 64 + lane, sum, f32);
        }
    }
}

// ---------------------------------------------------------------------------
// K7: gate half (c>=512): depthwise 3x3 directly from x.
// v2: lane = column, fully-coalesced row loads + __shfl for lane+-1 column
// neighbors. One block per (b,c) image; wave w owns rows w*16..w*16+15.
// 18 coalesced loads / 16 outputs per thread (was 18 strided / 4 outputs).
// ---------------------------------------------------------------------------
__global__ __launch_bounds__(256) void k_final_gate(const void* __restrict__ x,
                                                    const void* __restrict__ wDW,
                                                    const void* __restrict__ bDW,
                                                    const int* __restrict__ flag,
                                                    void* __restrict__ y) {
    const bool f32 = (*flag != 0);
    const int lane = threadIdx.x & 63;
    const int w    = threadIdx.x >> 6;
    const int c    = DM2 + blockIdx.x;
    const int b    = blockIdx.y;
    const size_t src = ((size_t)b * DM + c) * L_;

    float ww[3][3];
#pragma unroll
    for (int di = 0; di < 3; ++di)
#pragma unroll
        for (int dj = 0; dj < 3; ++dj) ww[di][dj] = ldv(wDW, c * 9 + di * 3 + dj, f32);
    const float bias = ldv(bDW, c, f32);

    const int r0 = w * 16;
    float vm[18], vl[18], vr[18];
#pragma unroll
    for (int k = 0; k < 18; ++k) {
        int rr = r0 - 1 + k;
        float v = (rr >= 0 && rr < H_) ? ldv(x, src + rr * W_ + lane, f32) : 0.f;
        vm[k] = v;
        float lf = __shfl_up(v, 1);
        float rt = __shfl_down(v, 1);
        vl[k] = (lane > 0)  ? lf : 0.f;
        vr[k] = (lane < 63) ? rt : 0.f;
    }
#pragma unroll
    for (int row = 0; row < 16; ++row) {
        float sum = bias;
#pragma unroll
        for (int di = 0; di < 3; ++di) {
            sum += ww[di][0] * vl[row + di]
                 + ww[di][1] * vm[row + di]
                 + ww[di][2] * vr[row + di];
        }
        stv(y, src + (r0 + row) * W_ + lane, sum, f32);
    }
}

// ---------------------------------------------------------------------------
// Workspace layout (42 MiB + 4 B):
//   [ 0,16M) BCdt_raw, then AB    [16M,24M) h partials
//   [24M,40M) BCdt_conv           [40M,42M) h fp32
//   [42M] dtype flag (int)
// ---------------------------------------------------------------------------
extern "C" void kernel_launch(void* const* d_in, const int* in_sizes, int n_in,
                              void* d_out, int out_size, void* d_ws, size_t ws_size,
                              hipStream_t stream) {
    const void* x      = d_in[0];
    const void* w_bcdt = d_in[1];
    const void* b_bcdt = d_in[2];
    const void* w_dw   = d_in[3];
    const void* b_dw   = d_in[4];
    const void* A      = d_in[5];
    const void* coeffs = d_in[6];
    const void* w_DW   = d_in[7];
    const void* b_DW   = d_in[8];

    char* ws = (char*)d_ws;
    float* f_raw  = (float*)ws;                          // 16 MiB (also AB)
    float* f_part = (float*)(ws + (size_t)(16 << 20));   // 8 MiB
    float* f_conv = (float*)(ws + (size_t)(24 << 20));   // 16 MiB
    float* f_hf   = (float*)(ws + (size_t)(40 << 20));   // 2 MiB
    int*   flag   = (int*)  (ws + (size_t)(42 << 20));   // 4 B

    k_detect    <<<1,               256, 0, stream>>>(x, flag);
    k_bcdt      <<<dim3(64, 16),    256, 0, stream>>>(x, w_bcdt, b_bcdt, flag, f_raw);
    k_dw_s      <<<16384,           256, 0, stream>>>(f_raw, w_dw, b_dw, flag, f_conv);
    k_softmax_ab<<<1024,            256, 0, stream>>>(f_conv, A, coeffs, flag, f_raw);
    k_hpart     <<<dim3(16, 4, 16), 256, 0, stream>>>(x, f_raw, flag, f_part);
    k_hred      <<<2048,            256, 0, stream>>>(f_part, flag, f_hf, d_out);
    k_y_ssm     <<<dim3(32, 8, 16), 256, 0, stream>>>(f_hf, f_conv, coeffs, w_DW, b_DW, flag, d_out);
    k_final_gate<<<dim3(512, 16),   256, 0, stream>>>(x, w_DW, b_DW, flag, d_out);
}

// Round 4
// 808.001 us; speedup vs baseline: 1.3326x; 1.0167x over previous
//
#include <hip/hip_runtime.h>
#include <hip/hip_bf16.h>

typedef __hip_bfloat16 bf16;

#define B_   16
#define DM   1024
#define DM2  512
#define L_   4096
#define S_   64
#define H_   64
#define W_   64

__device__ __forceinline__ float b2f(bf16 v) { return __bfloat162float(v); }

// dtype-agnostic element access: f32 ? float[] : bf16[]  (index in ELEMENTS)
__device__ __forceinline__ float ldv(const void* p, size_t i, bool f32) {
    return f32 ? ((const float*)p)[i] : b2f(((const bf16*)p)[i]);
}
__device__ __forceinline__ void stv(void* p, size_t i, float v, bool f32) {
    if (f32) ((float*)p)[i] = v;
    else     ((bf16*)p)[i] = __float2bfloat16(v);
}

// ---------------------------------------------------------------------------
// K0: detect input dtype. flag=1 -> fp32, flag=0 -> bf16.
// ---------------------------------------------------------------------------
__global__ __launch_bounds__(256) void k_detect(const void* __restrict__ x,
                                                int* __restrict__ flag) {
    const int t = threadIdx.x;
    float v = b2f(((const bf16*)x)[2 * t]);
    bool susp = !(fabsf(v) <= 100.f) || (v != 0.f && fabsf(v) < 1e-20f);
    unsigned long long m = __ballot(susp);
    __shared__ int cnt[4];
    if ((t & 63) == 0) cnt[t >> 6] = __popcll(m);
    __syncthreads();
    if (t == 0) *flag = (cnt[0] + cnt[1] + cnt[2] + cnt[3] > 32) ? 1 : 0;
}

// ---------------------------------------------------------------------------
// K1: BCdt_raw[b,s,l] = sum_d w_bcdt[s,d] * x[b,d,l] + b_bcdt[s]   (d < 512)
// 64-l tile per block -> grid (64,16) = 1024 blocks = 4 blocks/CU. w staged
// TRANSPOSED in LDS so the inner loop is two b128 reads + 16 FMA per k-step.
// ---------------------------------------------------------------------------
__global__ __launch_bounds__(256, 4) void k_bcdt(const void* __restrict__ x,
                                                 const void* __restrict__ w_bcdt,
                                                 const void* __restrict__ b_bcdt,
                                                 const int* __restrict__ flag,
                                                 float* __restrict__ raw) {
    const bool f32 = (*flag != 0);
    __shared__ alignas(16) float lx[32][68];   // [d-sub][l(64)+pad]
    __shared__ alignas(16) float lw[32][68];   // [d-sub][s(64)+pad] (w transposed)
    const int tid = threadIdx.x;
    const int l0  = blockIdx.x * 64;
    const int b   = blockIdx.y;
    const int ts  = tid >> 4;   // 0..15 -> s quad
    const int tl  = tid & 15;   // 0..15 -> l quad
    float4 acc[4];
#pragma unroll
    for (int i = 0; i < 4; ++i) acc[i] = make_float4(0.f, 0.f, 0.f, 0.f);
    const size_t xb = (size_t)b * DM * L_;
    for (int dk = 0; dk < DM2; dk += 32) {
#pragma unroll
        for (int k = 0; k < 8; ++k) {           // 32 d x 64 l
            int i = tid + k * 256;
            int di = i >> 6, li = i & 63;
            lx[di][li] = ldv(x, xb + (size_t)(dk + di) * L_ + l0 + li, f32);
        }
#pragma unroll
        for (int k = 0; k < 8; ++k) {           // 64 s x 32 d, stored transposed
            int i = tid + k * 256;
            int si = i >> 5, di = i & 31;
            lw[di][si] = ldv(w_bcdt, si * DM2 + dk + di, f32);
        }
        __syncthreads();
#pragma unroll
        for (int d = 0; d < 32; ++d) {
            float4 xv = ((const float4*)lx[d])[tl];
            float4 wv = *(const float4*)&lw[d][ts * 4];
            acc[0].x += wv.x * xv.x; acc[0].y += wv.x * xv.y;
            acc[0].z += wv.x * xv.z; acc[0].w += wv.x * xv.w;
            acc[1].x += wv.y * xv.x; acc[1].y += wv.y * xv.y;
            acc[1].z += wv.y * xv.z; acc[1].w += wv.y * xv.w;
            acc[2].x += wv.z * xv.x; acc[2].y += wv.z * xv.y;
            acc[2].z += wv.z * xv.z; acc[2].w += wv.z * xv.w;
            acc[3].x += wv.w * xv.x; acc[3].y += wv.w * xv.y;
            acc[3].z += wv.w * xv.z; acc[3].w += wv.w * xv.w;
        }
        __syncthreads();
    }
#pragma unroll
    for (int i = 0; i < 4; ++i) {
        int s = ts * 4 + i;
        float bias = ldv(b_bcdt, s, f32);
        acc[i].x += bias; acc[i].y += bias; acc[i].z += bias; acc[i].w += bias;
        ((float4*)(raw + (size_t)(b * S_ + s) * L_ + l0))[tl] = acc[i];
    }
}

// ---------------------------------------------------------------------------
// K2+K3 fused: per (b,s) image block. lane = column; 18 coalesced row loads
// per thread + __shfl for lane+-1; dwconv 3x3 in registers; block softmax;
// writes conv (for K6) and AB (in-place over raw: each block touches only
// its own row, and the softmax barriers separate all loads from all stores).
// ---------------------------------------------------------------------------
__global__ __launch_bounds__(256) void k_dwsm(const float* __restrict__ raw,
                                              const void* __restrict__ w_dw,
                                              const void* __restrict__ b_dw,
                                              const void* __restrict__ A,
                                              const void* __restrict__ coeffs,
                                              const int* __restrict__ flag,
                                              float* __restrict__ conv,
                                              float* __restrict__ ab) {
    const bool f32 = (*flag != 0);
    const int lane = threadIdx.x & 63;
    const int w    = threadIdx.x >> 6;
    const int s    = blockIdx.x;
    const int b    = blockIdx.y;
    const int bs   = b * S_ + s;
    const float* src = raw + (size_t)bs * L_;

    float ww[3][3];
#pragma unroll
    for (int di = 0; di < 3; ++di)
#pragma unroll
        for (int dj = 0; dj < 3; ++dj) ww[di][dj] = ldv(w_dw, s * 9 + di * 3 + dj, f32);
    const float bias = ldv(b_dw, s, f32);
    const float c0 = ldv(coeffs, 0, f32);
    const float c2 = ldv(coeffs, 2, f32);
    const float a  = ldv(A, s, f32);

    const int r0 = w * 16;
    float vm[18], vl[18], vr[18];
#pragma unroll
    for (int k = 0; k < 18; ++k) {
        int rr = r0 - 1 + k;
        float v = (rr >= 0 && rr < H_) ? src[rr * W_ + lane] : 0.f;
        vm[k] = v;
        float lf = __shfl_up(v, 1);
        float rt = __shfl_down(v, 1);
        vl[k] = (lane > 0)  ? lf : 0.f;
        vr[k] = (lane < 63) ? rt : 0.f;
    }
    float cv[16];
#pragma unroll
    for (int row = 0; row < 16; ++row) {
        float sum = bias;
#pragma unroll
        for (int di = 0; di < 3; ++di) {
            sum += ww[di][0] * vl[row + di]
                 + ww[di][1] * vm[row + di]
                 + ww[di][2] * vr[row + di];
        }
        cv[row] = sum;
    }

    // block softmax over the 4096 values of (c2*cv + a)
    float m = -1e30f;
#pragma unroll
    for (int k = 0; k < 16; ++k) m = fmaxf(m, c2 * cv[k] + a);
#pragma unroll
    for (int off = 32; off > 0; off >>= 1) m = fmaxf(m, __shfl_down(m, off));
    __shared__ float redm[4], redsum[4];
    if (lane == 0) redm[w] = m;
    __syncthreads();
    m = fmaxf(fmaxf(redm[0], redm[1]), fmaxf(redm[2], redm[3]));
    float e[16];
    float ssum = 0.f;
#pragma unroll
    for (int k = 0; k < 16; ++k) { e[k] = __expf(c2 * cv[k] + a - m); ssum += e[k]; }
#pragma unroll
    for (int off = 32; off > 0; off >>= 1) ssum += __shfl_down(ssum, off);
    if (lane == 0) redsum[w] = ssum;
    __syncthreads();
    ssum = redsum[0] + redsum[1] + redsum[2] + redsum[3];
    const float inv = 1.0f / ssum;

    float* cdst = conv + (size_t)bs * L_;
    float* adst = ab   + (size_t)bs * L_;
#pragma unroll
    for (int row = 0; row < 16; ++row) {
        int p = (r0 + row) * W_ + lane;
        cdst[p] = cv[row];
        adst[p] = e[row] * inv * (c0 * cv[row]);
    }
}

// ---------------------------------------------------------------------------
// K4: partial h: part[lc][b][d][s] = sum_{l in chunk} x[b,d,l] * AB[b,s,l]
// 32-d tile per block -> grid (16,4,16) = 1024 blocks = 4 blocks/CU.
// ---------------------------------------------------------------------------
__global__ __launch_bounds__(256, 4) void k_hpart(const void* __restrict__ x,
                                                  const float* __restrict__ ab,
                                                  const int* __restrict__ flag,
                                                  float* __restrict__ part) {
    const bool f32 = (*flag != 0);
    __shared__ alignas(16) float xt[32][36];   // [l][d(32)+pad]
    __shared__ alignas(16) float at[32][68];   // [l][s(64)+pad]
    const int tid = threadIdx.x;
    const int d0  = blockIdx.x * 32;
    const int lc  = blockIdx.y;
    const int b   = blockIdx.z;
    const int tdi = tid >> 4;   // 0..15 -> d pair
    const int tsi = tid & 15;   // 0..15 -> s quad
    float acc[2][4];
#pragma unroll
    for (int i = 0; i < 2; ++i)
#pragma unroll
        for (int j = 0; j < 4; ++j) acc[i][j] = 0.f;
    const size_t xb = (size_t)b * DM * L_ + (size_t)d0 * L_ + lc * 1024;
    const float* abb = ab + (size_t)b * S_ * L_ + lc * 1024;
    for (int l0 = 0; l0 < 1024; l0 += 32) {
#pragma unroll
        for (int k = 0; k < 4; ++k) {           // 32 d x 32 l
            int i = tid + k * 256;
            int di = i >> 5, li = i & 31;
            xt[li][di] = ldv(x, xb + (size_t)di * L_ + l0 + li, f32);
        }
#pragma unroll
        for (int k = 0; k < 8; ++k) {           // 64 s x 32 l
            int i = tid + k * 256;
            int si = i >> 5, li = i & 31;
            at[li][si] = abb[(size_t)si * L_ + l0 + li];
        }
        __syncthreads();
#pragma unroll
        for (int l = 0; l < 32; ++l) {
            float2 xv = *(const float2*)&xt[l][tdi * 2];
            float4 av = *(const float4*)&at[l][tsi * 4];
            acc[0][0] += xv.x * av.x; acc[0][1] += xv.x * av.y;
            acc[0][2] += xv.x * av.z; acc[0][3] += xv.x * av.w;
            acc[1][0] += xv.y * av.x; acc[1][1] += xv.y * av.y;
            acc[1][2] += xv.y * av.z; acc[1][3] += xv.y * av.w;
        }
        __syncthreads();
    }
    float* pp = part + ((size_t)lc * B_ + b) * DM2 * S_;
#pragma unroll
    for (int i = 0; i < 2; ++i) {
        int d = d0 + tdi * 2 + i;
        ((float4*)(pp + (size_t)d * S_))[tsi] =
            make_float4(acc[i][0], acc[i][1], acc[i][2], acc[i][3]);
    }
}

// ---------------------------------------------------------------------------
// K5: reduce the 4 partials -> h (fp32 ws for K6 feed, out-dtype to d_out)
// ---------------------------------------------------------------------------
__global__ __launch_bounds__(256) void k_hred(const float* __restrict__ part,
                                              const int* __restrict__ flag,
                                              float* __restrict__ hf,
                                              void* __restrict__ out) {
    const bool f32 = (*flag != 0);
    const int idx = blockIdx.x * 256 + threadIdx.x;    // 16*512*64
    const size_t stride = (size_t)B_ * DM2 * S_;
    float v = part[idx] + part[idx + stride] + part[idx + 2 * stride] + part[idx + 3 * stride];
    hf[idx] = v;
    stv(out, (size_t)B_ * DM * L_ + idx, v, f32);
}

// ---------------------------------------------------------------------------
// K6 (fused): for c<512, y = dwconv3x3(c1 * h[b,c,:] @ conv[b,:,:]) + b_DW.
// v3: 32-channel tile per block (grid 2048): halves conv staging traffic
// (668 -> 334 MB) and doubles FMA per staged byte. dwconv epilogue in
// registers + __shfl for lane+-1 column neighbors.
// ---------------------------------------------------------------------------
__global__ __launch_bounds__(256) void k_y_ssm(const float* __restrict__ hf,
                                               const float* __restrict__ conv,
                                               const void* __restrict__ coeffs,
                                               const void* __restrict__ wDW,
                                               const void* __restrict__ bDW,
                                               const int* __restrict__ flag,
                                               void* __restrict__ y) {
    const bool f32 = (*flag != 0);
    __shared__ alignas(16) float hsm[32][64];          // 8 KB
    __shared__ alignas(16) float convc[8][640];        // 20 KB

    const int tid  = threadIdx.x;
    const int lane = tid & 63;
    const int w    = tid >> 6;
    const int c0   = blockIdx.x * 32;
    const int r0   = blockIdx.y * 8;
    const int b    = blockIdx.z;

#pragma unroll
    for (int k = 0; k < 8; ++k) {
        int i = tid + k * 256;
        int c = i >> 6, s = i & 63;
        hsm[c][s] = hf[((size_t)b * DM2 + c0 + c) * S_ + s];
    }

    float acc[8][10];
#pragma unroll
    for (int c = 0; c < 8; ++c)
#pragma unroll
        for (int k = 0; k < 10; ++k) acc[c][k] = 0.f;

    const float* convb = conv + (size_t)b * S_ * L_;
    const int ls  = tid >> 5;
    const int lp  = tid & 31;

    for (int s0 = 0; s0 < S_; s0 += 8) {
        __syncthreads();
#pragma unroll
        for (int k = 0; k < 20; ++k) {
            int p  = lp + 32 * k;
            int gr = r0 - 1 + (p >> 6);
            gr = gr < 0 ? 0 : (gr > 63 ? 63 : gr);
            convc[ls][p] = convb[(size_t)(s0 + ls) * L_ + gr * 64 + (p & 63)];
        }
        __syncthreads();
#pragma unroll
        for (int s = 0; s < 8; ++s) {
            float hv[8];
#pragma unroll
            for (int c = 0; c < 8; ++c) hv[c] = hsm[w * 8 + c][s0 + s];
#pragma unroll
            for (int k = 0; k < 10; ++k) {
                float cvv = convc[s][lane + 64 * k];
#pragma unroll
                for (int c = 0; c < 8; ++c) acc[c][k] += hv[c] * cvv;
            }
        }
    }

    const float c1 = ldv(coeffs, 1, f32);
#pragma unroll
    for (int c8 = 0; c8 < 8; ++c8) {
        const int cl = w * 8 + c8;
        const int c  = c0 + cl;
        float ww[3][3];
#pragma unroll
        for (int di = 0; di < 3; ++di)
#pragma unroll
            for (int dj = 0; dj < 3; ++dj) ww[di][dj] = ldv(wDW, c * 9 + di * 3 + dj, f32);
        const float bias = ldv(bDW, c, f32);

        // scaled + row-boundary-masked column of 10 rows, in registers
        float vm[10], vl[10], vr[10];
#pragma unroll
        for (int k = 0; k < 10; ++k) {
            int gr = r0 - 1 + k;
            float v = (gr >= 0 && gr < H_) ? acc[c8][k] * c1 : 0.f;
            vm[k] = v;
            float lf = __shfl_up(v, 1);
            float rt = __shfl_down(v, 1);
            vl[k] = (lane > 0)  ? lf : 0.f;
            vr[k] = (lane < 63) ? rt : 0.f;
        }
#pragma unroll
        for (int row = 0; row < 8; ++row) {
            float sum = bias;
#pragma unroll
            for (int di = 0; di < 3; ++di) {
                sum += ww[di][0] * vl[row + di]
                     + ww[di][1] * vm[row + di]
                     + ww[di][2] * vr[row + di];
            }
            stv(y, ((size_t)b * DM + c) * L_ + (r0 + row) * 64 + lane, sum, f32);
        }
    }
}

// ---------------------------------------------------------------------------
// K7: gate half (c>=512): depthwise 3x3 directly from x.
// lane = column, fully-coalesced row loads + __shfl for lane+-1 column
// neighbors. One block per (b,c) image; wave w owns rows w*16..w*16+15.
// ---------------------------------------------------------------------------
__global__ __launch_bounds__(256) void k_final_gate(const void* __restrict__ x,
                                                    const void* __restrict__ wDW,
                                                    const void* __restrict__ bDW,
                                                    const int* __restrict__ flag,
                                                    void* __restrict__ y) {
    const bool f32 = (*flag != 0);
    const int lane = threadIdx.x & 63;
    const int w    = threadIdx.x >> 6;
    const int c    = DM2 + blockIdx.x;
    const int b    = blockIdx.y;
    const size_t src = ((size_t)b * DM + c) * L_;

    float ww[3][3];
#pragma unroll
    for (int di = 0; di < 3; ++di)
#pragma unroll
        for (int dj = 0; dj < 3; ++dj) ww[di][dj] = ldv(wDW, c * 9 + di * 3 + dj, f32);
    const float bias = ldv(bDW, c, f32);

    const int r0 = w * 16;
    float vm[18], vl[18], vr[18];
#pragma unroll
    for (int k = 0; k < 18; ++k) {
        int rr = r0 - 1 + k;
        float v = (rr >= 0 && rr < H_) ? ldv(x, src + rr * W_ + lane, f32) : 0.f;
        vm[k] = v;
        float lf = __shfl_up(v, 1);
        float rt = __shfl_down(v, 1);
        vl[k] = (lane > 0)  ? lf : 0.f;
        vr[k] = (lane < 63) ? rt : 0.f;
    }
#pragma unroll
    for (int row = 0; row < 16; ++row) {
        float sum = bias;
#pragma unroll
        for (int di = 0; di < 3; ++di) {
            sum += ww[di][0] * vl[row + di]
                 + ww[di][1] * vm[row + di]
                 + ww[di][2] * vr[row + di];
        }
        stv(y, src + (r0 + row) * W_ + lane, sum, f32);
    }
}

// ---------------------------------------------------------------------------
// Workspace layout (42 MiB + 4 B):
//   [ 0,16M) BCdt_raw, then AB    [16M,24M) h partials
//   [24M,40M) BCdt_conv           [40M,42M) h fp32
//   [42M] dtype flag (int)
// ---------------------------------------------------------------------------
extern "C" void kernel_launch(void* const* d_in, const int* in_sizes, int n_in,
                              void* d_out, int out_size, void* d_ws, size_t ws_size,
                              hipStream_t stream) {
    const void* x      = d_in[0];
    const void* w_bcdt = d_in[1];
    const void* b_bcdt = d_in[2];
    const void* w_dw   = d_in[3];
    const void* b_dw   = d_in[4];
    const void* A      = d_in[5];
    const void* coeffs = d_in[6];
    const void* w_DW   = d_in[7];
    const void* b_DW   = d_in[8];

    char* ws = (char*)d_ws;
    float* f_raw  = (float*)ws;                          // 16 MiB (also AB)
    float* f_part = (float*)(ws + (size_t)(16 << 20));   // 8 MiB
    float* f_conv = (float*)(ws + (size_t)(24 << 20));   // 16 MiB
    float* f_hf   = (float*)(ws + (size_t)(40 << 20));   // 2 MiB
    int*   flag   = (int*)  (ws + (size_t)(42 << 20));   // 4 B

    k_detect    <<<1,               256, 0, stream>>>(x, flag);
    k_bcdt      <<<dim3(64, 16),    256, 0, stream>>>(x, w_bcdt, b_bcdt, flag, f_raw);
    k_dwsm      <<<dim3(64, 16),    256, 0, stream>>>(f_raw, w_dw, b_dw, A, coeffs, flag, f_conv, f_raw);
    k_hpart     <<<dim3(16, 4, 16), 256, 0, stream>>>(x, f_raw, flag, f_part);
    k_hred      <<<2048,            256, 0, stream>>>(f_part, flag, f_hf, d_out);
    k_y_ssm     <<<dim3(16, 8, 16), 256, 0, stream>>>(f_hf, f_conv, coeffs, w_DW, b_DW, flag, d_out);
    k_final_gate<<<dim3(512, 16),   256, 0, stream>>>(x, w_DW, b_DW, flag, d_out);
}